// Round 2
// baseline (343.094 us; speedup 1.0000x reference)
//
#include <hip/hip_runtime.h>
#include <hip/hip_bf16.h>
#include <cstdint>

// ---------------------------------------------------------------------------
// MHA forward, fp32 in/out, bf16 MFMA internally.
// B=2 S=2048 D=1024 H=16 DH=64.
// Pipeline: cvt(fp32->bf16) x7 -> fused QKV GEMM -> flash attention -> out GEMM
// Workspace layout (56 MB):
//   [0,8M)   xq bf16 (later reused as ctx)   [8M,16M)  xk    [16M,24M) xv
//   [24M,32M) Qb      [32M,40M) Kb    [40M,48M) Vb
//   [48M,56M) Wq,Wk,Wv,Wo bf16 (2MB each)
// ---------------------------------------------------------------------------

typedef __attribute__((ext_vector_type(8))) __bf16 bf16x8;
typedef __attribute__((ext_vector_type(8))) unsigned short ushort8;
typedef __attribute__((ext_vector_type(4))) float f32x4;
typedef unsigned short ushort_t;

#define B_ 2
#define S_ 2048
#define D_ 1024
#define H_ 16
#define DH_ 64

__device__ __forceinline__ ushort_t f2b(float f) {
  uint32_t u = __builtin_bit_cast(uint32_t, f);
  u += 0x7fffu + ((u >> 16) & 1u);   // RNE
  return (ushort_t)(u >> 16);
}

__device__ __forceinline__ f32x4 mfma16(bf16x8 a, bf16x8 b, f32x4 c) {
  return __builtin_amdgcn_mfma_f32_16x16x32_bf16(a, b, c, 0, 0, 0);
}

// async global->LDS, 16B per lane. LDS dest is wave-uniform base + lane*16.
__device__ __forceinline__ void gload16(const ushort_t* g, char* lds) {
  __builtin_amdgcn_global_load_lds(
      (__attribute__((address_space(1))) void*)(uintptr_t)g,
      (__attribute__((address_space(3))) void*)(uintptr_t)lds, 16, 0, 0);
}

// ---------------------------------------------------------------------------
__global__ __launch_bounds__(256) void cvt_kernel(const float* __restrict__ src,
                                                  ushort_t* __restrict__ dst,
                                                  int n8) {
  int i = blockIdx.x * 256 + threadIdx.x;
  if (i >= n8) return;
  f32x4 a = ((const f32x4*)src)[i * 2];
  f32x4 b = ((const f32x4*)src)[i * 2 + 1];
  ushort8 o;
#pragma unroll
  for (int j = 0; j < 4; ++j) o[j] = f2b(a[j]);
#pragma unroll
  for (int j = 0; j < 4; ++j) o[4 + j] = f2b(b[j]);
  ((ushort8*)dst)[i] = o;
}

// ---------------------------------------------------------------------------
// GEMM: C[M,N] = A[M,K] * W[N,K]^T  (nn.Linear with B^T layout)
// BM=128 BN=64 BK=64, 256 threads (4 waves as 2x2 of 64x32 output each).
// LDS rows are 128B; swizzle: byte_in_row ^= (row&7)<<4. global_load_lds writes
// linearly, so the *source* slot is inverse-swizzled (same XOR involution).
#define BM 128
#define BN 64
#define BK 64

template <int OUTF32>
__device__ __forceinline__ void gemm_body(const ushort_t* __restrict__ A,
                                          const ushort_t* __restrict__ W,
                                          void* __restrict__ Cout,
                                          int M, int N, int K, int i0, int j0) {
  __shared__ char smem[BM * BK * 2 + BN * BK * 2];  // 16K + 8K
  char* sA = smem;
  char* sB = smem + BM * BK * 2;
  const int tid = threadIdx.x;
  const int w = tid >> 6, lane = tid & 63, l16 = lane & 15, lg = lane >> 4;
  const int wrow = (w >> 1) * 64, wcol = (w & 1) * 32;
  f32x4 acc[4][2] = {};
  const int nk = K / BK;
  for (int kt = 0; kt < nk; ++kt) {
    const int k0 = kt * BK;
    __syncthreads();  // previous tile fully consumed
    // stage A (128x64 bf16 = 16KB): 4 issues x 256 lanes x 16B
#pragma unroll
    for (int is = 0; is < 4; ++is) {
      int chunk = is * 256 + tid;      // linear 16B chunk in LDS
      int row = chunk >> 3, s = chunk & 7;
      int sl = s ^ (row & 7);          // inverse-swizzled source slot
      gload16(A + (size_t)(i0 + row) * K + k0 + sl * 8, sA + (is * 4 + w) * 1024);
    }
    // stage B (64x64 bf16 = 8KB): 2 issues
#pragma unroll
    for (int is = 0; is < 2; ++is) {
      int chunk = is * 256 + tid;
      int row = chunk >> 3, s = chunk & 7;
      int sl = s ^ (row & 7);
      gload16(W + (size_t)(j0 + row) * K + k0 + sl * 8, sB + (is * 4 + w) * 1024);
    }
    __syncthreads();  // compiler emits vmcnt(0) before barrier: tile ready
    bf16x8 af[4][2], bfr[2][2];
#pragma unroll
    for (int mi = 0; mi < 4; ++mi) {
      int r = wrow + mi * 16 + l16;
#pragma unroll
      for (int ks = 0; ks < 2; ++ks)
        af[mi][ks] = *(const bf16x8*)(sA + r * 128 + ((ks * 64 + lg * 16) ^ ((r & 7) << 4)));
    }
#pragma unroll
    for (int nj = 0; nj < 2; ++nj) {
      int r = wcol + nj * 16 + l16;
#pragma unroll
      for (int ks = 0; ks < 2; ++ks)
        bfr[nj][ks] = *(const bf16x8*)(sB + r * 128 + ((ks * 64 + lg * 16) ^ ((r & 7) << 4)));
    }
#pragma unroll
    for (int ks = 0; ks < 2; ++ks)
#pragma unroll
      for (int mi = 0; mi < 4; ++mi)
#pragma unroll
        for (int nj = 0; nj < 2; ++nj)
          acc[mi][nj] = mfma16(af[mi][ks], bfr[nj][ks], acc[mi][nj]);
  }
  // epilogue: C row = (lg*4+r), col = l16 within each 16x16 tile (m89 layout)
#pragma unroll
  for (int mi = 0; mi < 4; ++mi)
#pragma unroll
    for (int nj = 0; nj < 2; ++nj)
#pragma unroll
      for (int r = 0; r < 4; ++r) {
        int row = i0 + wrow + mi * 16 + lg * 4 + r;
        int col = j0 + wcol + nj * 16 + l16;
        if (OUTF32)
          ((float*)Cout)[(size_t)row * N + col] = acc[mi][nj][r];
        else
          ((ushort_t*)Cout)[(size_t)row * N + col] = f2b(acc[mi][nj][r]);
      }
}

__global__ __launch_bounds__(256) void qkv_gemm(
    const ushort_t* __restrict__ xq, const ushort_t* __restrict__ xk,
    const ushort_t* __restrict__ xv, const ushort_t* __restrict__ wq,
    const ushort_t* __restrict__ wk, const ushort_t* __restrict__ wv,
    ushort_t* __restrict__ q, ushort_t* __restrict__ k, ushort_t* __restrict__ v) {
  int z = blockIdx.z;
  const ushort_t* A = z == 0 ? xq : (z == 1 ? xk : xv);
  const ushort_t* W = z == 0 ? wq : (z == 1 ? wk : wv);
  ushort_t* C = z == 0 ? q : (z == 1 ? k : v);
  gemm_body<0>(A, W, C, B_ * S_, D_, D_, blockIdx.y * BM, blockIdx.x * BN);
}

__global__ __launch_bounds__(256) void out_gemm(const ushort_t* __restrict__ ctx,
                                                const ushort_t* __restrict__ wo,
                                                float* __restrict__ out) {
  gemm_body<1>(ctx, wo, out, B_ * S_, D_, D_, blockIdx.y * BM, blockIdx.x * BN);
}

// ---------------------------------------------------------------------------
// Flash attention, causal. grid = (S/64, B*H), 256 threads = 4 waves.
// Block owns 64 q-rows (wave w: rows q0=qt*64+w*16 .. +15). KV tiles of 64.
// LDS: K[64][128B] swizzled (async-staged), Vt[64(dh)][128B] swizzled
// (reg-staged transpose), P per-wave [16][128B] swizzled.
__global__ __launch_bounds__(256) void attn_kernel(
    const ushort_t* __restrict__ Qb, const ushort_t* __restrict__ Kb,
    const ushort_t* __restrict__ Vb, ushort_t* __restrict__ ctx) {
  const int qt = blockIdx.x;
  const int bh = blockIdx.y;
  const int b = bh >> 4, h = bh & 15;
  const int tid = threadIdx.x;
  const int w = tid >> 6, lane = tid & 63, l16 = lane & 15, lg = lane >> 4;

  __shared__ char smem[8192 + 8192 + 4 * 2048];
  char* sK = smem;
  char* sVt = smem + 8192;
  char* sP = smem + 16384 + w * 2048;

  const size_t base = ((size_t)b * S_) * D_ + h * DH_;  // element offset of row 0

  // Q fragments (A-frag: row=l16, k = ks*32 + lg*8 + j), held in regs
  const int q0 = qt * 64 + w * 16;
  bf16x8 qf[2];
  {
    const ushort_t* qrow = Qb + base + (size_t)(q0 + l16) * D_;
    qf[0] = *(const bf16x8*)(qrow + lg * 8);
    qf[1] = *(const bf16x8*)(qrow + 32 + lg * 8);
  }

  f32x4 acc_o[4] = {};
  float m[4], lsum[4];
#pragma unroll
  for (int r = 0; r < 4; ++r) { m[r] = -1e30f; lsum[r] = 0.f; }

  for (int t = 0; t <= qt; ++t) {
    __syncthreads();  // previous tile's LDS fully consumed
    // stage K via global_load_lds (row-major swizzled: linear dest,
    // inverse-swizzled source slot) and V^T (reg-staged transpose, swizzled)
#pragma unroll
    for (int it = 0; it < 2; ++it) {
      int chunk = it * 256 + tid;        // 512 chunks of 16B
      int row = chunk >> 3, s = chunk & 7;
      int sl = s ^ (row & 7);
      gload16(Kb + base + (size_t)(t * 64 + row) * D_ + sl * 8,
              sK + (it * 4 + w) * 1024);
      const ushort_t* gv = Vb + base + (size_t)(t * 64 + row) * D_ + s * 8;
      ushort8 vv = *(const ushort8*)gv;
#pragma unroll
      for (int j = 0; j < 8; ++j) {
        int col = s * 8 + j;  // dh index -> Vt row
        *(ushort_t*)(sVt + col * 128 + ((row * 2) ^ ((col & 7) << 4))) = vv[j];
      }
    }
    __syncthreads();

    // S = Q K^T / sqrt(DH)
    f32x4 sc[4] = {};
#pragma unroll
    for (int ks = 0; ks < 2; ++ks)
#pragma unroll
      for (int nt = 0; nt < 4; ++nt) {
        int rk = nt * 16 + l16;  // kv row in tile
        bf16x8 kf = *(const bf16x8*)(sK + rk * 128 + ((ks * 64 + lg * 16) ^ ((rk & 7) << 4)));
        sc[nt] = mfma16(qf[ks], kf, sc[nt]);
      }
    const bool diag = (t == qt);
#pragma unroll
    for (int nt = 0; nt < 4; ++nt)
#pragma unroll
      for (int r = 0; r < 4; ++r) {
        float s_ = sc[nt][r] * 0.125f;
        if (diag) {
          int kg = t * 64 + nt * 16 + l16;
          int qg = q0 + lg * 4 + r;
          if (kg > qg) s_ = -1e30f;
        }
        sc[nt][r] = s_;
      }
    // row max (reduce over the 16 lanes of the column group)
    float alpha[4];
#pragma unroll
    for (int r = 0; r < 4; ++r) {
      float v = fmaxf(fmaxf(sc[0][r], sc[1][r]), fmaxf(sc[2][r], sc[3][r]));
      v = fmaxf(v, __shfl_xor(v, 1));
      v = fmaxf(v, __shfl_xor(v, 2));
      v = fmaxf(v, __shfl_xor(v, 4));
      v = fmaxf(v, __shfl_xor(v, 8));
      float mn = fmaxf(m[r], v);
      alpha[r] = __expf(m[r] - mn);
      m[r] = mn;
    }
    // P = exp(S-m): accumulate row sums, write bf16 P to per-wave LDS
    float rsum[4] = {0.f, 0.f, 0.f, 0.f};
#pragma unroll
    for (int nt = 0; nt < 4; ++nt)
#pragma unroll
      for (int r = 0; r < 4; ++r) {
        float p = __expf(sc[nt][r] - m[r]);
        rsum[r] += p;
        int prow = lg * 4 + r;
        int kv = nt * 16 + l16;
        *(ushort_t*)(sP + prow * 128 + ((kv * 2) ^ ((prow & 7) << 4))) = f2b(p);
      }
#pragma unroll
    for (int r = 0; r < 4; ++r) {
      float v = rsum[r];
      v += __shfl_xor(v, 1);
      v += __shfl_xor(v, 2);
      v += __shfl_xor(v, 4);
      v += __shfl_xor(v, 8);
      lsum[r] = lsum[r] * alpha[r] + v;
    }
#pragma unroll
    for (int nt = 0; nt < 4; ++nt)
#pragma unroll
      for (int r = 0; r < 4; ++r) acc_o[nt][r] *= alpha[r];
    // O += P V  (A-frag of P from per-wave LDS; B-frag = Vt rows)
#pragma unroll
    for (int ks = 0; ks < 2; ++ks) {
      int pr = l16;
      bf16x8 pa = *(const bf16x8*)(sP + pr * 128 + ((ks * 64 + lg * 16) ^ ((pr & 7) << 4)));
#pragma unroll
      for (int nt = 0; nt < 4; ++nt) {
        int dr = nt * 16 + l16;
        bf16x8 vb = *(const bf16x8*)(sVt + dr * 128 + ((ks * 64 + lg * 16) ^ ((dr & 7) << 4)));
        acc_o[nt] = mfma16(pa, vb, acc_o[nt]);
      }
    }
  }
  // epilogue: divide by lsum, write ctx bf16
#pragma unroll
  for (int r = 0; r < 4; ++r) {
    float inv = 1.f / lsum[r];
    int qg = q0 + lg * 4 + r;
    ushort_t* crow = ctx + base + (size_t)qg * D_;
#pragma unroll
    for (int nt = 0; nt < 4; ++nt) crow[nt * 16 + l16] = f2b(acc_o[nt][r] * inv);
  }
}

// ---------------------------------------------------------------------------
extern "C" void kernel_launch(void* const* d_in, const int* in_sizes, int n_in,
                              void* d_out, int out_size, void* d_ws, size_t ws_size,
                              hipStream_t stream) {
  const float* query = (const float*)d_in[0];
  const float* key   = (const float*)d_in[1];
  const float* value = (const float*)d_in[2];
  const float* Wq    = (const float*)d_in[3];
  const float* Wk    = (const float*)d_in[4];
  const float* Wv    = (const float*)d_in[5];
  const float* Wo    = (const float*)d_in[6];

  char* ws = (char*)d_ws;
  const size_t SZ = (size_t)B_ * S_ * D_ * 2;  // 8 MB
  const size_t WSZ = (size_t)D_ * D_ * 2;      // 2 MB
  ushort_t* xq  = (ushort_t*)(ws + 0 * SZ);
  ushort_t* xk  = (ushort_t*)(ws + 1 * SZ);
  ushort_t* xv  = (ushort_t*)(ws + 2 * SZ);
  ushort_t* Qb  = (ushort_t*)(ws + 3 * SZ);
  ushort_t* Kb  = (ushort_t*)(ws + 4 * SZ);
  ushort_t* Vb  = (ushort_t*)(ws + 5 * SZ);
  ushort_t* ctx = xq;  // xq is dead after qkv_gemm; alias to save 8 MB
  ushort_t* wqb = (ushort_t*)(ws + 6 * SZ + 0 * WSZ);
  ushort_t* wkb = (ushort_t*)(ws + 6 * SZ + 1 * WSZ);
  ushort_t* wvb = (ushort_t*)(ws + 6 * SZ + 2 * WSZ);
  ushort_t* wob = (ushort_t*)(ws + 6 * SZ + 3 * WSZ);

  const int n8a = B_ * S_ * D_ / 8;  // 524288
  const int n8w = D_ * D_ / 8;       // 131072
  cvt_kernel<<<n8a / 256, 256, 0, stream>>>(query, xq, n8a);
  cvt_kernel<<<n8a / 256, 256, 0, stream>>>(key, xk, n8a);
  cvt_kernel<<<n8a / 256, 256, 0, stream>>>(value, xv, n8a);
  cvt_kernel<<<n8w / 256, 256, 0, stream>>>(Wq, wqb, n8w);
  cvt_kernel<<<n8w / 256, 256, 0, stream>>>(Wk, wkb, n8w);
  cvt_kernel<<<n8w / 256, 256, 0, stream>>>(Wv, wvb, n8w);
  cvt_kernel<<<n8w / 256, 256, 0, stream>>>(Wo, wob, n8w);

  qkv_gemm<<<dim3(D_ / BN, B_ * S_ / BM, 3), 256, 0, stream>>>(
      xq, xk, xv, wqb, wkb, wvb, Qb, Kb, Vb);

  attn_kernel<<<dim3(S_ / 64, B_ * H_), 256, 0, stream>>>(Qb, Kb, Vb, ctx);

  out_gemm<<<dim3(D_ / BN, B_ * S_ / BM), 256, 0, stream>>>(ctx, wob, (float*)d_out);
}

// Round 3
// 341.784 us; speedup vs baseline: 1.0038x; 1.0038x over previous
//
#include <hip/hip_runtime.h>
#include <hip/hip_bf16.h>
#include <cstdint>

// ---------------------------------------------------------------------------
// MHA forward, fp32 in/out, bf16 MFMA internally.
// B=2 S=2048 D=1024 H=16 DH=64.
// Pipeline: cvt x7 -> Q,K proj (BT gemm) -> V proj TRANSPOSED (operand-swap)
//           -> flash attention (2 waves/32 q-rows, Vt staged via gload16)
//           -> out proj.
// Workspace (56 MB):
//   [0,8M) xq (reused as ctx) [8,16) xk [16,24) xv
//   [24,32) Qb [32,40) Kb [40,48) Vt[D][B*S] [48,56) weights bf16 x4
// ---------------------------------------------------------------------------

typedef __attribute__((ext_vector_type(8))) __bf16 bf16x8;
typedef __attribute__((ext_vector_type(8))) unsigned short ushort8;
typedef __attribute__((ext_vector_type(4))) float f32x4;
typedef unsigned short ushort_t;

#define B_ 2
#define S_ 2048
#define D_ 1024
#define H_ 16
#define DH_ 64

__device__ __forceinline__ ushort_t f2b(float f) {
  uint32_t u = __builtin_bit_cast(uint32_t, f);
  u += 0x7fffu + ((u >> 16) & 1u);   // RNE
  return (ushort_t)(u >> 16);
}

__device__ __forceinline__ f32x4 mfma16(bf16x8 a, bf16x8 b, f32x4 c) {
  return __builtin_amdgcn_mfma_f32_16x16x32_bf16(a, b, c, 0, 0, 0);
}

// async global->LDS, 16B/lane: dest = wave-uniform base + lane*16 (linear).
__device__ __forceinline__ void gload16(const ushort_t* g, char* lds) {
  __builtin_amdgcn_global_load_lds(
      (__attribute__((address_space(1))) void*)(uintptr_t)g,
      (__attribute__((address_space(3))) void*)(uintptr_t)lds, 16, 0, 0);
}

// ---------------------------------------------------------------------------
__global__ __launch_bounds__(256) void cvt_kernel(const float* __restrict__ src,
                                                  ushort_t* __restrict__ dst,
                                                  int n8) {
  int i = blockIdx.x * 256 + threadIdx.x;
  if (i >= n8) return;
  f32x4 a = ((const f32x4*)src)[i * 2];
  f32x4 b = ((const f32x4*)src)[i * 2 + 1];
  ushort8 o;
#pragma unroll
  for (int j = 0; j < 4; ++j) o[j] = f2b(a[j]);
#pragma unroll
  for (int j = 0; j < 4; ++j) o[4 + j] = f2b(b[j]);
  ((ushort8*)dst)[i] = o;
}

// ---------------------------------------------------------------------------
// C[M,N] = scale * A[M,K] * W[N,K]^T. m97 structure: BM=BN=128, BK=64,
// 4 waves as 2x2, each 64x64 output (4x4 16x16 frags).
// LDS rows 128B, swizzle byte^=(row&7)<<4; gload16 dest linear, source slot
// inverse-swizzled (rule #21).
#define BM 128
#define BN 128
#define BK 64

template <int OUTF32>
__device__ __forceinline__ void gemm_body(const ushort_t* __restrict__ A,
                                          const ushort_t* __restrict__ W,
                                          void* __restrict__ Cout,
                                          int M, int N, int K, float scale) {
  __shared__ char smem[BM * BK * 2 + BN * BK * 2];  // 16K + 16K
  char* sA = smem;
  char* sB = smem + BM * BK * 2;
  const int i0 = blockIdx.y * BM, j0 = blockIdx.x * BN;
  const int tid = threadIdx.x;
  const int w = tid >> 6, lane = tid & 63, l16 = lane & 15, lg = lane >> 4;
  const int wr = (w >> 1) * 64, wc = (w & 1) * 64;
  f32x4 acc[4][4] = {};
  const int nk = K / BK;
  for (int kt = 0; kt < nk; ++kt) {
    const int k0 = kt * BK;
    __syncthreads();  // prev tile fully consumed
#pragma unroll
    for (int is = 0; is < 4; ++is) {  // A: 128x64 bf16 = 1024 chunks
      int chunk = is * 256 + tid;
      int row = chunk >> 3, s = chunk & 7, sl = s ^ (row & 7);
      gload16(A + (size_t)(i0 + row) * K + k0 + sl * 8, sA + (is * 4 + w) * 1024);
    }
#pragma unroll
    for (int is = 0; is < 4; ++is) {  // B: 128x64
      int chunk = is * 256 + tid;
      int row = chunk >> 3, s = chunk & 7, sl = s ^ (row & 7);
      gload16(W + (size_t)(j0 + row) * K + k0 + sl * 8, sB + (is * 4 + w) * 1024);
    }
    __syncthreads();  // barrier drains vmcnt: tile ready
#pragma unroll
    for (int ks = 0; ks < 2; ++ks) {
      bf16x8 af[4], bfr[4];
#pragma unroll
      for (int mi = 0; mi < 4; ++mi) {
        int r = wr + mi * 16 + l16;
        af[mi] = *(const bf16x8*)(sA + r * 128 + ((ks * 64 + lg * 16) ^ ((r & 7) << 4)));
      }
#pragma unroll
      for (int nj = 0; nj < 4; ++nj) {
        int r = wc + nj * 16 + l16;
        bfr[nj] = *(const bf16x8*)(sB + r * 128 + ((ks * 64 + lg * 16) ^ ((r & 7) << 4)));
      }
#pragma unroll
      for (int mi = 0; mi < 4; ++mi)
#pragma unroll
        for (int nj = 0; nj < 4; ++nj)
          acc[mi][nj] = mfma16(af[mi], bfr[nj], acc[mi][nj]);
    }
  }
  // epilogue: within 16x16 frag, row = lg*4+r, col = l16 (m89 layout)
#pragma unroll
  for (int mi = 0; mi < 4; ++mi)
#pragma unroll
    for (int nj = 0; nj < 4; ++nj)
#pragma unroll
      for (int r = 0; r < 4; ++r) {
        int row = i0 + wr + mi * 16 + lg * 4 + r;
        int col = j0 + wc + nj * 16 + l16;
        float v = acc[mi][nj][r] * scale;
        if (OUTF32)
          ((float*)Cout)[(size_t)row * N + col] = v;
        else
          ((ushort_t*)Cout)[(size_t)row * N + col] = f2b(v);
      }
}

template <int OUTF32>
__global__ __launch_bounds__(256) void gemm_bt(const ushort_t* __restrict__ A,
                                               const ushort_t* __restrict__ W,
                                               void* __restrict__ C,
                                               int M, int N, int K, float scale) {
  gemm_body<OUTF32>(A, W, C, M, N, K, scale);
}

// ---------------------------------------------------------------------------
// Flash attention, causal. grid = (S/32, B*H), 128 threads = 2 waves.
// Wave w owns 16 q-rows (q0 = qt*32 + w*16). KV tiles of 64.
// LDS: sK[64][128B] swizzled (gload16), sVt[64 dh][128B kv] swizzled (gload16
// from pre-transposed Vt), sP per-wave [16][128B].
// Q is pre-scaled by 1/sqrt(DH) in the projection epilogue.
__global__ __launch_bounds__(128) void attn_kernel(
    const ushort_t* __restrict__ Qb, const ushort_t* __restrict__ Kb,
    const ushort_t* __restrict__ VtG, ushort_t* __restrict__ ctx) {
  const int qt = blockIdx.x;          // 32-row q tile, 0..63
  const int bh = blockIdx.y;
  const int b = bh >> 4, h = bh & 15;
  const int tid = threadIdx.x;
  const int w = tid >> 6, lane = tid & 63, l16 = lane & 15, lg = lane >> 4;

  __shared__ char smem[8192 + 8192 + 2 * 2048];
  char* sK = smem;
  char* sVt = smem + 8192;
  char* sP = smem + 16384 + w * 2048;

  const size_t BS = (size_t)B_ * S_;
  const size_t qkbase = ((size_t)b * S_) * D_ + h * DH_;
  const int q0 = qt * 32 + w * 16;

  // Q fragments (A-frag: row=l16, k = ks*32 + lg*8 + j)
  bf16x8 qf[2];
  {
    const ushort_t* qrow = Qb + qkbase + (size_t)(q0 + l16) * D_;
    qf[0] = *(const bf16x8*)(qrow + lg * 8);
    qf[1] = *(const bf16x8*)(qrow + 32 + lg * 8);
  }

  f32x4 acc_o[4] = {};
  float m[4], lsum[4];
#pragma unroll
  for (int r = 0; r < 4; ++r) { m[r] = -1e30f; lsum[r] = 0.f; }

  const int tlast = (qt * 32 + 31) >> 6;
  for (int t = 0; t <= tlast; ++t) {
    __syncthreads();  // prev tile LDS fully consumed
    const ushort_t* Ksrc = Kb + qkbase + (size_t)(t * 64) * D_;
    const ushort_t* Vsrc = VtG + (size_t)(h * 64) * BS + (size_t)b * S_ + t * 64;
#pragma unroll
    for (int it = 0; it < 4; ++it) {
      int chunk = it * 128 + tid;  // 512 chunks of 16B per operand
      int row = chunk >> 3, s = chunk & 7, sl = s ^ (row & 7);
      gload16(Ksrc + (size_t)row * D_ + sl * 8, sK + (it * 2 + w) * 1024);
      gload16(Vsrc + (size_t)row * BS + sl * 8, sVt + (it * 2 + w) * 1024);
    }
    __syncthreads();

    // S = Q K^T (Q pre-scaled)
    f32x4 sc[4] = {};
#pragma unroll
    for (int ks = 0; ks < 2; ++ks)
#pragma unroll
      for (int nt = 0; nt < 4; ++nt) {
        int rk = nt * 16 + l16;
        bf16x8 kf = *(const bf16x8*)(sK + rk * 128 + ((ks * 64 + lg * 16) ^ ((rk & 7) << 4)));
        sc[nt] = mfma16(qf[ks], kf, sc[nt]);
      }
    if (t == tlast) {  // causal mask only on the diagonal tile
#pragma unroll
      for (int nt = 0; nt < 4; ++nt)
#pragma unroll
        for (int r = 0; r < 4; ++r) {
          int kg = t * 64 + nt * 16 + l16;
          int qg = q0 + lg * 4 + r;
          if (kg > qg) sc[nt][r] = -1e30f;
        }
    }
    // online softmax: row max over the 16-lane column group
    float alpha[4];
#pragma unroll
    for (int r = 0; r < 4; ++r) {
      float v = fmaxf(fmaxf(sc[0][r], sc[1][r]), fmaxf(sc[2][r], sc[3][r]));
      v = fmaxf(v, __shfl_xor(v, 1));
      v = fmaxf(v, __shfl_xor(v, 2));
      v = fmaxf(v, __shfl_xor(v, 4));
      v = fmaxf(v, __shfl_xor(v, 8));
      float mn = fmaxf(m[r], v);
      alpha[r] = __expf(m[r] - mn);
      m[r] = mn;
    }
    float rsum[4] = {0.f, 0.f, 0.f, 0.f};
#pragma unroll
    for (int nt = 0; nt < 4; ++nt)
#pragma unroll
      for (int r = 0; r < 4; ++r) {
        float p = __expf(sc[nt][r] - m[r]);
        rsum[r] += p;
        int prow = lg * 4 + r;
        int kv = nt * 16 + l16;
        *(ushort_t*)(sP + prow * 128 + ((kv * 2) ^ ((prow & 7) << 4))) = f2b(p);
      }
#pragma unroll
    for (int r = 0; r < 4; ++r) {
      float v = rsum[r];
      v += __shfl_xor(v, 1);
      v += __shfl_xor(v, 2);
      v += __shfl_xor(v, 4);
      v += __shfl_xor(v, 8);
      lsum[r] = lsum[r] * alpha[r] + v;
    }
#pragma unroll
    for (int nt = 0; nt < 4; ++nt)
#pragma unroll
      for (int r = 0; r < 4; ++r) acc_o[nt][r] *= alpha[r];
    // O += P V: A-frag = P rows (per-wave sP), B-frag = Vt rows (d along kv)
#pragma unroll
    for (int ks = 0; ks < 2; ++ks) {
      bf16x8 pa = *(const bf16x8*)(sP + l16 * 128 + ((ks * 64 + lg * 16) ^ ((l16 & 7) << 4)));
#pragma unroll
      for (int nt = 0; nt < 4; ++nt) {
        int dr = nt * 16 + l16;
        bf16x8 vb = *(const bf16x8*)(sVt + dr * 128 + ((ks * 64 + lg * 16) ^ ((dr & 7) << 4)));
        acc_o[nt] = mfma16(pa, vb, acc_o[nt]);
      }
    }
  }
  // epilogue
#pragma unroll
  for (int r = 0; r < 4; ++r) {
    float inv = 1.f / lsum[r];
    int qg = q0 + lg * 4 + r;
    ushort_t* crow = ctx + qkbase + (size_t)qg * D_;
#pragma unroll
    for (int nt = 0; nt < 4; ++nt) crow[nt * 16 + l16] = f2b(acc_o[nt][r] * inv);
  }
}

// ---------------------------------------------------------------------------
extern "C" void kernel_launch(void* const* d_in, const int* in_sizes, int n_in,
                              void* d_out, int out_size, void* d_ws, size_t ws_size,
                              hipStream_t stream) {
  const float* query = (const float*)d_in[0];
  const float* key   = (const float*)d_in[1];
  const float* value = (const float*)d_in[2];
  const float* Wq    = (const float*)d_in[3];
  const float* Wk    = (const float*)d_in[4];
  const float* Wv    = (const float*)d_in[5];
  const float* Wo    = (const float*)d_in[6];

  char* ws = (char*)d_ws;
  const size_t SZ = (size_t)B_ * S_ * D_ * 2;  // 8 MB
  const size_t WSZ = (size_t)D_ * D_ * 2;      // 2 MB
  ushort_t* xq  = (ushort_t*)(ws + 0 * SZ);
  ushort_t* xk  = (ushort_t*)(ws + 1 * SZ);
  ushort_t* xv  = (ushort_t*)(ws + 2 * SZ);
  ushort_t* Qb  = (ushort_t*)(ws + 3 * SZ);
  ushort_t* Kb  = (ushort_t*)(ws + 4 * SZ);
  ushort_t* Vt  = (ushort_t*)(ws + 5 * SZ);  // [D][B*S] pre-transposed V
  ushort_t* ctx = xq;                        // xq dead after Q projection
  ushort_t* wqb = (ushort_t*)(ws + 6 * SZ + 0 * WSZ);
  ushort_t* wkb = (ushort_t*)(ws + 6 * SZ + 1 * WSZ);
  ushort_t* wvb = (ushort_t*)(ws + 6 * SZ + 2 * WSZ);
  ushort_t* wob = (ushort_t*)(ws + 6 * SZ + 3 * WSZ);

  const int n8a = B_ * S_ * D_ / 8;
  const int n8w = D_ * D_ / 8;
  cvt_kernel<<<n8a / 256, 256, 0, stream>>>(query, xq, n8a);
  cvt_kernel<<<n8a / 256, 256, 0, stream>>>(key, xk, n8a);
  cvt_kernel<<<n8a / 256, 256, 0, stream>>>(value, xv, n8a);
  cvt_kernel<<<n8w / 256, 256, 0, stream>>>(Wq, wqb, n8w);
  cvt_kernel<<<n8w / 256, 256, 0, stream>>>(Wk, wkb, n8w);
  cvt_kernel<<<n8w / 256, 256, 0, stream>>>(Wv, wvb, n8w);
  cvt_kernel<<<n8w / 256, 256, 0, stream>>>(Wo, wob, n8w);

  const float qscale = 0.125f;  // 1/sqrt(DH), folded into Q projection
  dim3 gQK(D_ / BN, (B_ * S_) / BM);          // (8, 32)
  gemm_bt<0><<<gQK, 256, 0, stream>>>(xq, wqb, Qb, B_ * S_, D_, D_, qscale);
  gemm_bt<0><<<gQK, 256, 0, stream>>>(xk, wkb, Kb, B_ * S_, D_, D_, 1.f);
  // V projection, output transposed: Vt[d][s] = sum_k Wv[d][k] * xv[s][k]
  dim3 gVt((B_ * S_) / BN, D_ / BM);          // (32, 8)
  gemm_bt<0><<<gVt, 256, 0, stream>>>(wvb, xv, Vt, D_, B_ * S_, D_, 1.f);

  attn_kernel<<<dim3(S_ / 32, B_ * H_), 128, 0, stream>>>(Qb, Kb, Vt, ctx);

  gemm_bt<1><<<gQK, 256, 0, stream>>>(ctx, wob, (float*)d_out, B_ * S_, D_, D_, 1.f);
}

// Round 4
// 241.189 us; speedup vs baseline: 1.4225x; 1.4171x over previous
//
#include <hip/hip_runtime.h>
#include <hip/hip_bf16.h>
#include <cstdint>

// ---------------------------------------------------------------------------
// MHA forward, fp32 in/out, bf16 MFMA internally.
// B=2 S=2048 D=1024 H=16 DH=64.
// cvt x2 (fused) -> QKV proj (one dispatch, V transposed via operand swap)
// -> flash attention (4 waves, dbuf staging, causal-paired grid) -> out proj.
// Workspace (56 MB):
//   [0,8M) xq (reused as ctx) [8,16) xk [16,24) xv
//   [24,32) Qb [32,40) Kb [40,48) Vt[D][B*S] [48,56) weights bf16 x4
// ---------------------------------------------------------------------------

typedef __attribute__((ext_vector_type(8))) __bf16 bf16x8;
typedef __attribute__((ext_vector_type(8))) unsigned short ushort8;
typedef __attribute__((ext_vector_type(4))) float f32x4;
typedef unsigned short ushort_t;

#define B_ 2
#define S_ 2048
#define D_ 1024
#define H_ 16
#define DH_ 64
#define BK 64

// 1/sqrt(DH) * log2(e): scores land pre-scaled for exp2-domain softmax
#define QSCALE 0.1803368801111244f

__device__ __forceinline__ ushort_t f2b(float f) {
  uint32_t u = __builtin_bit_cast(uint32_t, f);
  u += 0x7fffu + ((u >> 16) & 1u);   // RNE
  return (ushort_t)(u >> 16);
}

__device__ __forceinline__ f32x4 mfma16(bf16x8 a, bf16x8 b, f32x4 c) {
  return __builtin_amdgcn_mfma_f32_16x16x32_bf16(a, b, c, 0, 0, 0);
}

// async global->LDS, 16B/lane: dest = wave-uniform base + lane*16 (linear).
__device__ __forceinline__ void gload16(const ushort_t* g, char* lds) {
  __builtin_amdgcn_global_load_lds(
      (__attribute__((address_space(1))) void*)(uintptr_t)g,
      (__attribute__((address_space(3))) void*)(uintptr_t)lds, 16, 0, 0);
}

// ---------------------------------------------------------------------------
// Fused fp32->bf16 converts: blockIdx.y selects the tensor.
__global__ __launch_bounds__(256) void cvt3_kernel(
    const float* __restrict__ s0, const float* __restrict__ s1,
    const float* __restrict__ s2, ushort_t* __restrict__ d0,
    ushort_t* __restrict__ d1, ushort_t* __restrict__ d2) {
  const float* src = blockIdx.y == 0 ? s0 : (blockIdx.y == 1 ? s1 : s2);
  ushort_t* dst = blockIdx.y == 0 ? d0 : (blockIdx.y == 1 ? d1 : d2);
  int i = blockIdx.x * 256 + threadIdx.x;
  f32x4 a = ((const f32x4*)src)[i * 2];
  f32x4 b = ((const f32x4*)src)[i * 2 + 1];
  ushort8 o;
#pragma unroll
  for (int j = 0; j < 4; ++j) o[j] = f2b(a[j]);
#pragma unroll
  for (int j = 0; j < 4; ++j) o[4 + j] = f2b(b[j]);
  ((ushort8*)dst)[i] = o;
}

__global__ __launch_bounds__(256) void cvt4_kernel(
    const float* __restrict__ s0, const float* __restrict__ s1,
    const float* __restrict__ s2, const float* __restrict__ s3,
    ushort_t* __restrict__ d0, ushort_t* __restrict__ d1,
    ushort_t* __restrict__ d2, ushort_t* __restrict__ d3) {
  const float* src = blockIdx.y == 0 ? s0
                     : (blockIdx.y == 1 ? s1 : (blockIdx.y == 2 ? s2 : s3));
  ushort_t* dst = blockIdx.y == 0 ? d0
                  : (blockIdx.y == 1 ? d1 : (blockIdx.y == 2 ? d2 : d3));
  int i = blockIdx.x * 256 + threadIdx.x;
  f32x4 a = ((const f32x4*)src)[i * 2];
  f32x4 b = ((const f32x4*)src)[i * 2 + 1];
  ushort8 o;
#pragma unroll
  for (int j = 0; j < 4; ++j) o[j] = f2b(a[j]);
#pragma unroll
  for (int j = 0; j < 4; ++j) o[4 + j] = f2b(b[j]);
  ((ushort8*)dst)[i] = o;
}

// ---------------------------------------------------------------------------
// C[M,N] = scale * A[M,K] * W[N,K]^T. m97 structure, templated tile.
// 4 waves as 2x2, each (TBM/2)x(TBN/2). LDS rows 128B, swizzle
// byte^=(row&7)<<4; gload16 dest linear, source slot inverse-swizzled.
template <int TBM, int TBN, int OUTF32>
__device__ __forceinline__ void gemm_body(const ushort_t* __restrict__ A,
                                          const ushort_t* __restrict__ W,
                                          void* __restrict__ Cout,
                                          int M, int N, int K, float scale,
                                          int i0, int j0) {
  constexpr int MI = TBM / 32, NJ = TBN / 32;
  __shared__ char smem[(TBM + TBN) * BK * 2];
  char* sA = smem;
  char* sB = smem + TBM * BK * 2;
  const int tid = threadIdx.x;
  const int w = tid >> 6, lane = tid & 63, l16 = lane & 15, lg = lane >> 4;
  const int wr = (w >> 1) * (TBM / 2), wc = (w & 1) * (TBN / 2);
  f32x4 acc[MI][NJ] = {};
  const int nk = K / BK;
  for (int kt = 0; kt < nk; ++kt) {
    const int k0 = kt * BK;
    __syncthreads();  // prev tile fully consumed
#pragma unroll
    for (int is = 0; is < MI; ++is) {
      int chunk = is * 256 + tid;
      int row = chunk >> 3, s = chunk & 7, sl = s ^ (row & 7);
      gload16(A + (size_t)(i0 + row) * K + k0 + sl * 8, sA + (is * 4 + w) * 1024);
    }
#pragma unroll
    for (int is = 0; is < NJ; ++is) {
      int chunk = is * 256 + tid;
      int row = chunk >> 3, s = chunk & 7, sl = s ^ (row & 7);
      gload16(W + (size_t)(j0 + row) * K + k0 + sl * 8, sB + (is * 4 + w) * 1024);
    }
    __syncthreads();  // barrier drains vmcnt: tile ready
#pragma unroll
    for (int ks = 0; ks < 2; ++ks) {
      bf16x8 af[MI], bfr[NJ];
#pragma unroll
      for (int mi = 0; mi < MI; ++mi) {
        int r = wr + mi * 16 + l16;
        af[mi] = *(const bf16x8*)(sA + r * 128 + ((ks * 64 + lg * 16) ^ ((r & 7) << 4)));
      }
#pragma unroll
      for (int nj = 0; nj < NJ; ++nj) {
        int r = wc + nj * 16 + l16;
        bfr[nj] = *(const bf16x8*)(sB + r * 128 + ((ks * 64 + lg * 16) ^ ((r & 7) << 4)));
      }
#pragma unroll
      for (int mi = 0; mi < MI; ++mi)
#pragma unroll
        for (int nj = 0; nj < NJ; ++nj)
          acc[mi][nj] = mfma16(af[mi], bfr[nj], acc[mi][nj]);
    }
  }
  // epilogue: within 16x16 frag, row = lg*4+r, col = l16 (m89 layout)
#pragma unroll
  for (int mi = 0; mi < MI; ++mi)
#pragma unroll
    for (int nj = 0; nj < NJ; ++nj)
#pragma unroll
      for (int r = 0; r < 4; ++r) {
        int row = i0 + wr + mi * 16 + lg * 4 + r;
        int col = j0 + wc + nj * 16 + l16;
        float v = acc[mi][nj][r] * scale;
        if (OUTF32)
          ((float*)Cout)[(size_t)row * N + col] = v;
        else
          ((ushort_t*)Cout)[(size_t)row * N + col] = f2b(v);
      }
}

// One dispatch for Q, K, and transposed-V projections. grid (32, 8, 3).
__global__ __launch_bounds__(256) void qkv_gemm(
    const ushort_t* __restrict__ xq, const ushort_t* __restrict__ xk,
    const ushort_t* __restrict__ xv, const ushort_t* __restrict__ wq,
    const ushort_t* __restrict__ wk, const ushort_t* __restrict__ wv,
    ushort_t* __restrict__ Qb, ushort_t* __restrict__ Kb,
    ushort_t* __restrict__ Vt) {
  const int z = blockIdx.z;
  if (z < 2) {
    // y = x @ W^T : M=B*S rows (blockIdx.x), N=D cols (blockIdx.y)
    gemm_body<128, 128, 0>(z ? xk : xq, z ? wk : wq, z ? Kb : Qb,
                           B_ * S_, D_, D_, z ? 1.f : QSCALE,
                           blockIdx.x * 128, blockIdx.y * 128);
  } else {
    // Vt[d][s] = sum_k Wv[d][k] * xv[s][k] : operand swap, M=D, N=B*S
    gemm_body<128, 128, 0>(wv, xv, Vt, D_, B_ * S_, D_, 1.f,
                           blockIdx.y * 128, blockIdx.x * 128);
  }
}

__global__ __launch_bounds__(256) void out_gemm(const ushort_t* __restrict__ ctx,
                                                const ushort_t* __restrict__ wo,
                                                float* __restrict__ out) {
  gemm_body<128, 64, 1>(ctx, wo, out, B_ * S_, D_, D_, 1.f,
                        blockIdx.y * 128, blockIdx.x * 64);
}

// ---------------------------------------------------------------------------
// Flash attention, causal, exp2-domain softmax (Q pre-scaled by QSCALE).
// grid = (16 pairs, B*H), 256 threads = 4 waves. Block handles q-tiles
// {p, 31-p} (64 rows each) sequentially -> every block = 33 KV-tile iters.
// Double-buffered K/Vt staging via gload16: issue(t+1) -> compute(t) ->
// one barrier (drains vmcnt) per tile.
// LDS: buf[2] x (sK[64][128B] + sVt[64][128B]) = 32KB, sP 4x2KB = 8KB.
__global__ __launch_bounds__(256) void attn_kernel(
    const ushort_t* __restrict__ Qb, const ushort_t* __restrict__ Kb,
    const ushort_t* __restrict__ VtG, ushort_t* __restrict__ ctx) {
  const int pair = blockIdx.x;
  const int bh = blockIdx.y;
  const int b = bh >> 4, h = bh & 15;
  const int tid = threadIdx.x;
  const int w = tid >> 6, lane = tid & 63, l16 = lane & 15, lg = lane >> 4;

  __shared__ char smem[2 * 16384 + 4 * 2048];
  char* sP = smem + 32768 + w * 2048;

  const size_t BS = (size_t)B_ * S_;
  const size_t qkbase = ((size_t)b * S_) * D_ + h * DH_;
  const ushort_t* Vbase = VtG + (size_t)(h * 64) * BS + (size_t)b * S_;

  for (int sub = 0; sub < 2; ++sub) {
    const int qt = sub ? (31 - pair) : pair;
    const int q0 = qt * 64 + w * 16;
    const int tl = qt;  // diagonal tile index

    // Q fragments (A-frag: row=l16, k = ks*32 + lg*8 + j)
    bf16x8 qf[2];
    {
      const ushort_t* qrow = Qb + qkbase + (size_t)(q0 + l16) * D_;
      qf[0] = *(const bf16x8*)(qrow + lg * 8);
      qf[1] = *(const bf16x8*)(qrow + 32 + lg * 8);
    }

    f32x4 acc_o[4] = {};
    float m[4], lsum[4];
#pragma unroll
    for (int r = 0; r < 4; ++r) { m[r] = -1e30f; lsum[r] = 0.f; }

    int cur = 0;
    // stage tile 0 -> buf 0
    {
      const ushort_t* Ksrc = Kb + qkbase;
      const ushort_t* Vsrc = Vbase;
#pragma unroll
      for (int it = 0; it < 2; ++it) {
        int chunk = it * 256 + tid;
        int row = chunk >> 3, s = chunk & 7, sl = s ^ (row & 7);
        gload16(Ksrc + (size_t)row * D_ + sl * 8, smem + (it * 4 + w) * 1024);
        gload16(Vsrc + (size_t)row * BS + sl * 8, smem + 8192 + (it * 4 + w) * 1024);
      }
    }
    __syncthreads();  // drains vmcnt: tile 0 ready

    for (int t = 0; t <= tl; ++t) {
      // issue next tile's staging into the other buffer (overlaps compute)
      if (t < tl) {
        char* bK = smem + (cur ^ 1) * 16384;
        const ushort_t* Ksrc = Kb + qkbase + (size_t)((t + 1) * 64) * D_;
        const ushort_t* Vsrc = Vbase + (t + 1) * 64;
#pragma unroll
        for (int it = 0; it < 2; ++it) {
          int chunk = it * 256 + tid;
          int row = chunk >> 3, s = chunk & 7, sl = s ^ (row & 7);
          gload16(Ksrc + (size_t)row * D_ + sl * 8, bK + (it * 4 + w) * 1024);
          gload16(Vsrc + (size_t)row * BS + sl * 8, bK + 8192 + (it * 4 + w) * 1024);
        }
      }
      char* bK = smem + cur * 16384;
      char* bV = bK + 8192;

      // S = Q K^T (pre-scaled, log2 domain)
      f32x4 sc[4] = {};
#pragma unroll
      for (int ks = 0; ks < 2; ++ks)
#pragma unroll
        for (int nt = 0; nt < 4; ++nt) {
          int rk = nt * 16 + l16;
          bf16x8 kf = *(const bf16x8*)(bK + rk * 128 + ((ks * 64 + lg * 16) ^ ((rk & 7) << 4)));
          sc[nt] = mfma16(qf[ks], kf, sc[nt]);
        }
      if (t == tl) {  // causal mask on the diagonal tile
#pragma unroll
        for (int nt = 0; nt < 4; ++nt)
#pragma unroll
          for (int r = 0; r < 4; ++r) {
            int kg = t * 64 + nt * 16 + l16;
            int qg = q0 + lg * 4 + r;
            if (kg > qg) sc[nt][r] = -1e30f;
          }
      }
      // online softmax: row max over the 16-lane column group
      float alpha[4];
#pragma unroll
      for (int r = 0; r < 4; ++r) {
        float v = fmaxf(fmaxf(sc[0][r], sc[1][r]), fmaxf(sc[2][r], sc[3][r]));
        v = fmaxf(v, __shfl_xor(v, 1));
        v = fmaxf(v, __shfl_xor(v, 2));
        v = fmaxf(v, __shfl_xor(v, 4));
        v = fmaxf(v, __shfl_xor(v, 8));
        float mn = fmaxf(m[r], v);
        alpha[r] = exp2f(m[r] - mn);
        m[r] = mn;
      }
      float rsum[4] = {0.f, 0.f, 0.f, 0.f};
#pragma unroll
      for (int nt = 0; nt < 4; ++nt)
#pragma unroll
        for (int r = 0; r < 4; ++r) {
          float p = exp2f(sc[nt][r] - m[r]);
          rsum[r] += p;
          int prow = lg * 4 + r;
          int kv = nt * 16 + l16;
          *(ushort_t*)(sP + prow * 128 + ((kv * 2) ^ ((prow & 7) << 4))) = f2b(p);
        }
#pragma unroll
      for (int r = 0; r < 4; ++r) {
        float v = rsum[r];
        v += __shfl_xor(v, 1);
        v += __shfl_xor(v, 2);
        v += __shfl_xor(v, 4);
        v += __shfl_xor(v, 8);
        lsum[r] = lsum[r] * alpha[r] + v;
      }
#pragma unroll
      for (int nt = 0; nt < 4; ++nt)
#pragma unroll
        for (int r = 0; r < 4; ++r) acc_o[nt][r] *= alpha[r];
      // O += P V: A-frag = P rows (per-wave sP), B-frag = Vt rows
#pragma unroll
      for (int ks = 0; ks < 2; ++ks) {
        bf16x8 pa = *(const bf16x8*)(sP + l16 * 128 + ((ks * 64 + lg * 16) ^ ((l16 & 7) << 4)));
#pragma unroll
        for (int nt = 0; nt < 4; ++nt) {
          int dr = nt * 16 + l16;
          bf16x8 vb = *(const bf16x8*)(bV + dr * 128 + ((ks * 64 + lg * 16) ^ ((dr & 7) << 4)));
          acc_o[nt] = mfma16(pa, vb, acc_o[nt]);
        }
      }
      __syncthreads();  // all waves done with buf cur; next tile staged
      cur ^= 1;
    }
    // epilogue: normalize, write ctx bf16
#pragma unroll
    for (int r = 0; r < 4; ++r) {
      float inv = 1.f / lsum[r];
      int qg = q0 + lg * 4 + r;
      ushort_t* crow = ctx + qkbase + (size_t)qg * D_;
#pragma unroll
      for (int nt = 0; nt < 4; ++nt) crow[nt * 16 + l16] = f2b(acc_o[nt][r] * inv);
    }
  }
}

// ---------------------------------------------------------------------------
extern "C" void kernel_launch(void* const* d_in, const int* in_sizes, int n_in,
                              void* d_out, int out_size, void* d_ws, size_t ws_size,
                              hipStream_t stream) {
  const float* query = (const float*)d_in[0];
  const float* key   = (const float*)d_in[1];
  const float* value = (const float*)d_in[2];
  const float* Wq    = (const float*)d_in[3];
  const float* Wk    = (const float*)d_in[4];
  const float* Wv    = (const float*)d_in[5];
  const float* Wo    = (const float*)d_in[6];

  char* ws = (char*)d_ws;
  const size_t SZ = (size_t)B_ * S_ * D_ * 2;  // 8 MB
  const size_t WSZ = (size_t)D_ * D_ * 2;      // 2 MB
  ushort_t* xq  = (ushort_t*)(ws + 0 * SZ);
  ushort_t* xk  = (ushort_t*)(ws + 1 * SZ);
  ushort_t* xv  = (ushort_t*)(ws + 2 * SZ);
  ushort_t* Qb  = (ushort_t*)(ws + 3 * SZ);
  ushort_t* Kb  = (ushort_t*)(ws + 4 * SZ);
  ushort_t* Vt  = (ushort_t*)(ws + 5 * SZ);  // [D][B*S] pre-transposed V
  ushort_t* ctx = xq;                        // xq dead after QKV projection
  ushort_t* wqb = (ushort_t*)(ws + 6 * SZ + 0 * WSZ);
  ushort_t* wkb = (ushort_t*)(ws + 6 * SZ + 1 * WSZ);
  ushort_t* wvb = (ushort_t*)(ws + 6 * SZ + 2 * WSZ);
  ushort_t* wob = (ushort_t*)(ws + 6 * SZ + 3 * WSZ);

  const int n8a = B_ * S_ * D_ / 8;  // 524288
  const int n8w = D_ * D_ / 8;       // 131072
  cvt3_kernel<<<dim3(n8a / 256, 3), 256, 0, stream>>>(query, key, value, xq, xk, xv);
  cvt4_kernel<<<dim3(n8w / 256, 4), 256, 0, stream>>>(Wq, Wk, Wv, Wo, wqb, wkb, wvb, wob);

  qkv_gemm<<<dim3(32, 8, 3), 256, 0, stream>>>(xq, xk, xv, wqb, wkb, wvb, Qb, Kb, Vt);

  attn_kernel<<<dim3(16, B_ * H_), 256, 0, stream>>>(Qb, Kb, Vt, ctx);

  out_gemm<<<dim3(D_ / 64, (B_ * S_) / 128), 256, 0, stream>>>(ctx, wob, (float*)d_out);
}

// Round 8
// 217.536 us; speedup vs baseline: 1.5772x; 1.1087x over previous
//
#include <hip/hip_runtime.h>
#include <hip/hip_bf16.h>
#include <cstdint>

// ---------------------------------------------------------------------------
// MHA forward, fp32 in/out, bf16 MFMA internally.
// B=2 S=2048 D=1024 H=16 DH=64.
// R4..R7: attn uses SWAPPED QK^T (lane-local q-rows: cheap softmax reduce,
//     b64 P-writes), defer-rescale, setprio, XCD-local grid (bh fastest).
//     out_gemm = dbuf single-barrier variant (A/B vs qkv's 2-barrier).
// Workspace (56 MB): [0,8M) xq/ctx [8,16) xk [16,24) xv
//   [24,32) Qb [32,40) Kb [40,48) Vt[D][B*S] [48,56) weights bf16 x4
// ---------------------------------------------------------------------------

typedef __attribute__((ext_vector_type(8))) __bf16 bf16x8;
typedef __attribute__((ext_vector_type(8))) unsigned short ushort8;
typedef __attribute__((ext_vector_type(4))) unsigned short usv4;
typedef __attribute__((ext_vector_type(4))) float f32x4;
typedef unsigned short ushort_t;

#define B_ 2
#define S_ 2048
#define D_ 1024
#define H_ 16
#define DH_ 64
#define BK 64

// 1/sqrt(DH) * log2(e): scores land pre-scaled for exp2-domain softmax
#define QSCALE 0.1803368801111244f

__device__ __forceinline__ ushort_t f2b(float f) {  // RNE
  uint32_t u = __builtin_bit_cast(uint32_t, f);
  u += 0x7fffu + ((u >> 16) & 1u);
  return (ushort_t)(u >> 16);
}
__device__ __forceinline__ ushort_t f2bf(float f) {  // round-nearest (no tie-even)
  uint32_t u = __builtin_bit_cast(uint32_t, f);
  return (ushort_t)((u + 0x8000u) >> 16);
}

__device__ __forceinline__ f32x4 mfma16(bf16x8 a, bf16x8 b, f32x4 c) {
  return __builtin_amdgcn_mfma_f32_16x16x32_bf16(a, b, c, 0, 0, 0);
}

// async global->LDS, 16B/lane: dest = wave-uniform base + lane*16 (linear).
__device__ __forceinline__ void gload16(const ushort_t* g, char* lds) {
  __builtin_amdgcn_global_load_lds(
      (__attribute__((address_space(1))) void*)(uintptr_t)g,
      (__attribute__((address_space(3))) void*)(uintptr_t)lds, 16, 0, 0);
}

// ---------------------------------------------------------------------------
__global__ __launch_bounds__(256) void cvt3_kernel(
    const float* __restrict__ s0, const float* __restrict__ s1,
    const float* __restrict__ s2, ushort_t* __restrict__ d0,
    ushort_t* __restrict__ d1, ushort_t* __restrict__ d2) {
  const float* src = blockIdx.y == 0 ? s0 : (blockIdx.y == 1 ? s1 : s2);
  ushort_t* dst = blockIdx.y == 0 ? d0 : (blockIdx.y == 1 ? d1 : d2);
  int i = blockIdx.x * 256 + threadIdx.x;
  f32x4 a = ((const f32x4*)src)[i * 2];
  f32x4 b = ((const f32x4*)src)[i * 2 + 1];
  ushort8 o;
#pragma unroll
  for (int j = 0; j < 4; ++j) o[j] = f2b(a[j]);
#pragma unroll
  for (int j = 0; j < 4; ++j) o[4 + j] = f2b(b[j]);
  ((ushort8*)dst)[i] = o;
}

__global__ __launch_bounds__(256) void cvt4_kernel(
    const float* __restrict__ s0, const float* __restrict__ s1,
    const float* __restrict__ s2, const float* __restrict__ s3,
    ushort_t* __restrict__ d0, ushort_t* __restrict__ d1,
    ushort_t* __restrict__ d2, ushort_t* __restrict__ d3) {
  const float* src = blockIdx.y == 0 ? s0
                     : (blockIdx.y == 1 ? s1 : (blockIdx.y == 2 ? s2 : s3));
  ushort_t* dst = blockIdx.y == 0 ? d0
                  : (blockIdx.y == 1 ? d1 : (blockIdx.y == 2 ? d2 : d3));
  int i = blockIdx.x * 256 + threadIdx.x;
  f32x4 a = ((const f32x4*)src)[i * 2];
  f32x4 b = ((const f32x4*)src)[i * 2 + 1];
  ushort8 o;
#pragma unroll
  for (int j = 0; j < 4; ++j) o[j] = f2b(a[j]);
#pragma unroll
  for (int j = 0; j < 4; ++j) o[4 + j] = f2b(b[j]);
  ((ushort8*)dst)[i] = o;
}

// ---------------------------------------------------------------------------
// C[M,N] = scale * A[M,K] * W[N,K]^T.  4 waves as 2x2. LDS rows 128B,
// swizzle byte^=(row&7)<<4; gload16 dest linear, source slot inv-swizzled.
// Variant A (qkv): m97 2-barrier single-buffer.
template <int TBM, int TBN, int OUTF32>
__device__ __forceinline__ void gemm_body(const ushort_t* __restrict__ A,
                                          const ushort_t* __restrict__ W,
                                          void* __restrict__ Cout,
                                          int M, int N, int K, float scale,
                                          int i0, int j0) {
  constexpr int MI = TBM / 32, NJ = TBN / 32;
  __shared__ char smem[(TBM + TBN) * BK * 2];
  char* sA = smem;
  char* sB = smem + TBM * BK * 2;
  const int tid = threadIdx.x;
  const int w = tid >> 6, lane = tid & 63, l16 = lane & 15, lg = lane >> 4;
  const int wr = (w >> 1) * (TBM / 2), wc = (w & 1) * (TBN / 2);
  f32x4 acc[MI][NJ] = {};
  const int nk = K / BK;
  for (int kt = 0; kt < nk; ++kt) {
    const int k0 = kt * BK;
    __syncthreads();
#pragma unroll
    for (int is = 0; is < MI; ++is) {
      int chunk = is * 256 + tid;
      int row = chunk >> 3, s = chunk & 7, sl = s ^ (row & 7);
      gload16(A + (size_t)(i0 + row) * K + k0 + sl * 8, sA + (is * 4 + w) * 1024);
    }
#pragma unroll
    for (int is = 0; is < NJ; ++is) {
      int chunk = is * 256 + tid;
      int row = chunk >> 3, s = chunk & 7, sl = s ^ (row & 7);
      gload16(W + (size_t)(j0 + row) * K + k0 + sl * 8, sB + (is * 4 + w) * 1024);
    }
    __syncthreads();
#pragma unroll
    for (int ks = 0; ks < 2; ++ks) {
      bf16x8 af[MI], bfr[NJ];
#pragma unroll
      for (int mi = 0; mi < MI; ++mi) {
        int r = wr + mi * 16 + l16;
        af[mi] = *(const bf16x8*)(sA + r * 128 + ((ks * 64 + lg * 16) ^ ((r & 7) << 4)));
      }
#pragma unroll
      for (int nj = 0; nj < NJ; ++nj) {
        int r = wc + nj * 16 + l16;
        bfr[nj] = *(const bf16x8*)(sB + r * 128 + ((ks * 64 + lg * 16) ^ ((r & 7) << 4)));
      }
#pragma unroll
      for (int mi = 0; mi < MI; ++mi)
#pragma unroll
        for (int nj = 0; nj < NJ; ++nj)
          acc[mi][nj] = mfma16(af[mi], bfr[nj], acc[mi][nj]);
    }
  }
#pragma unroll
  for (int mi = 0; mi < MI; ++mi)
#pragma unroll
    for (int nj = 0; nj < NJ; ++nj)
#pragma unroll
      for (int r = 0; r < 4; ++r) {
        int row = i0 + wr + mi * 16 + lg * 4 + r;
        int col = j0 + wc + nj * 16 + l16;
        float v = acc[mi][nj][r] * scale;
        if (OUTF32)
          ((float*)Cout)[(size_t)row * N + col] = v;
        else
          ((ushort_t*)Cout)[(size_t)row * N + col] = f2b(v);
      }
}

// Variant B (out): double-buffered, stage(t+1) -> compute(t) -> 1 barrier.
template <int TBM, int TBN, int OUTF32>
__device__ __forceinline__ void gemm_db(const ushort_t* __restrict__ A,
                                        const ushort_t* __restrict__ W,
                                        void* __restrict__ Cout,
                                        int M, int N, int K, float scale,
                                        int i0, int j0) {
  constexpr int MI = TBM / 32, NJ = TBN / 32;
  constexpr int BUFB = (TBM + TBN) * BK * 2;
  __shared__ char smem[2 * BUFB];
  const int tid = threadIdx.x;
  const int w = tid >> 6, lane = tid & 63, l16 = lane & 15, lg = lane >> 4;
  const int wr = (w >> 1) * (TBM / 2), wc = (w & 1) * (TBN / 2);
  f32x4 acc[MI][NJ] = {};
  const int nk = K / BK;

  auto stage = [&](int kt, int buf) {
    char* sA = smem + buf * BUFB;
    char* sB = sA + TBM * BK * 2;
    const int k0 = kt * BK;
#pragma unroll
    for (int is = 0; is < MI; ++is) {
      int chunk = is * 256 + tid;
      int row = chunk >> 3, s = chunk & 7, sl = s ^ (row & 7);
      gload16(A + (size_t)(i0 + row) * K + k0 + sl * 8, sA + (is * 4 + w) * 1024);
    }
#pragma unroll
    for (int is = 0; is < NJ; ++is) {
      int chunk = is * 256 + tid;
      int row = chunk >> 3, s = chunk & 7, sl = s ^ (row & 7);
      gload16(W + (size_t)(j0 + row) * K + k0 + sl * 8, sB + (is * 4 + w) * 1024);
    }
  };

  stage(0, 0);
  __syncthreads();
  int cur = 0;
  for (int kt = 0; kt < nk; ++kt) {
    if (kt + 1 < nk) stage(kt + 1, cur ^ 1);
    char* sA = smem + cur * BUFB;
    char* sB = sA + TBM * BK * 2;
#pragma unroll
    for (int ks = 0; ks < 2; ++ks) {
      bf16x8 af[MI], bfr[NJ];
#pragma unroll
      for (int mi = 0; mi < MI; ++mi) {
        int r = wr + mi * 16 + l16;
        af[mi] = *(const bf16x8*)(sA + r * 128 + ((ks * 64 + lg * 16) ^ ((r & 7) << 4)));
      }
#pragma unroll
      for (int nj = 0; nj < NJ; ++nj) {
        int r = wc + nj * 16 + l16;
        bfr[nj] = *(const bf16x8*)(sB + r * 128 + ((ks * 64 + lg * 16) ^ ((r & 7) << 4)));
      }
#pragma unroll
      for (int mi = 0; mi < MI; ++mi)
#pragma unroll
        for (int nj = 0; nj < NJ; ++nj)
          acc[mi][nj] = mfma16(af[mi], bfr[nj], acc[mi][nj]);
    }
    __syncthreads();  // drains vmcnt: next buf ready; all waves done with cur
    cur ^= 1;
  }
#pragma unroll
  for (int mi = 0; mi < MI; ++mi)
#pragma unroll
    for (int nj = 0; nj < NJ; ++nj)
#pragma unroll
      for (int r = 0; r < 4; ++r) {
        int row = i0 + wr + mi * 16 + lg * 4 + r;
        int col = j0 + wc + nj * 16 + l16;
        float v = acc[mi][nj][r] * scale;
        if (OUTF32)
          ((float*)Cout)[(size_t)row * N + col] = v;
        else
          ((ushort_t*)Cout)[(size_t)row * N + col] = f2b(v);
      }
}

// One dispatch for Q, K, and transposed-V projections. grid (32, 8, 3).
__global__ __launch_bounds__(256) void qkv_gemm(
    const ushort_t* __restrict__ xq, const ushort_t* __restrict__ xk,
    const ushort_t* __restrict__ xv, const ushort_t* __restrict__ wq,
    const ushort_t* __restrict__ wk, const ushort_t* __restrict__ wv,
    ushort_t* __restrict__ Qb, ushort_t* __restrict__ Kb,
    ushort_t* __restrict__ Vt) {
  const int z = blockIdx.z;
  if (z < 2) {
    gemm_body<128, 128, 0>(z ? xk : xq, z ? wk : wq, z ? Kb : Qb,
                           B_ * S_, D_, D_, z ? 1.f : QSCALE,
                           blockIdx.x * 128, blockIdx.y * 128);
  } else {
    // Vt[d][s] = sum_k Wv[d][k] * xv[s][k] : operand swap, M=D, N=B*S
    gemm_body<128, 128, 0>(wv, xv, Vt, D_, B_ * S_, D_, 1.f,
                           blockIdx.y * 128, blockIdx.x * 128);
  }
}

__global__ __launch_bounds__(256) void out_gemm(const ushort_t* __restrict__ ctx,
                                                const ushort_t* __restrict__ wo,
                                                float* __restrict__ out) {
  gemm_db<128, 64, 1>(ctx, wo, out, B_ * S_, D_, D_, 1.f,
                      blockIdx.y * 128, blockIdx.x * 64);
}

// ---------------------------------------------------------------------------
// Flash attention, causal, exp2-domain, SWAPPED QK^T.
// grid = (B*H, 16 pairs) -> linear%8 = bh%8 -> 4 heads per XCD (K/V L2-local).
// 256 threads = 4 waves; block does q-tiles {p, 31-p} (64 rows each), 33 iters.
// Swapped St = mfma(K,Q): col=q=l16 (lane-local q-row), row=kv=lg*4+r+16nt.
// LDS: dbuf (sK[64][128B] + sVt[64][128B]) x2 = 32KB, sP 4x2KB.
__global__ __launch_bounds__(256) void attn_kernel(
    const ushort_t* __restrict__ Qb, const ushort_t* __restrict__ Kb,
    const ushort_t* __restrict__ VtG, ushort_t* __restrict__ ctx) {
  const int bh = blockIdx.x;
  const int pair = blockIdx.y;
  const int b = bh >> 4, h = bh & 15;
  const int tid = threadIdx.x;
  const int w = tid >> 6, lane = tid & 63, l16 = lane & 15, lg = lane >> 4;

  __shared__ char smem[2 * 16384 + 4 * 2048];
  char* sP = smem + 32768 + w * 2048;

  const size_t BS = (size_t)B_ * S_;
  const size_t qkbase = ((size_t)b * S_) * D_ + h * DH_;
  const ushort_t* Vbase = VtG + (size_t)(h * 64) * BS + (size_t)b * S_;

  // staging offsets (per-thread constants)
  const int srow = tid >> 3, sslot = (tid & 7) ^ (srow & 7);
  const size_t koff0 = (size_t)srow * D_ + sslot * 8;
  const size_t koff1 = koff0 + (size_t)32 * D_;
  const size_t voff0 = (size_t)srow * BS + sslot * 8;
  const size_t voff1 = voff0 + (size_t)32 * BS;
  const int dst0 = w * 1024, dst1 = 4096 + w * 1024;

  // P-write swizzled byte offsets (per nt), and A-frag read offsets
  const int pwsw = (l16 & 7) << 4;
  const int pbase = l16 * 128;

  for (int sub = 0; sub < 2; ++sub) {
    const int qt = sub ? (31 - pair) : pair;
    const int q0 = qt * 64 + w * 16;
    const int qg0 = q0 + l16;  // this lane's q row (swapped layout)
    const int tl = qt;

    bf16x8 qf[2];
    {
      const ushort_t* qrow = Qb + qkbase + (size_t)qg0 * D_;
      qf[0] = *(const bf16x8*)(qrow + lg * 8);
      qf[1] = *(const bf16x8*)(qrow + 32 + lg * 8);
    }

    f32x4 acc_o[4] = {};
    float m = -1e30f, lsum = 0.f;

    int cur = 0;
    {  // stage tile 0 -> buf 0
      const ushort_t* Ksrc = Kb + qkbase;
      gload16(Ksrc + koff0, smem + dst0);
      gload16(Ksrc + koff1, smem + dst1);
      gload16(Vbase + voff0, smem + 8192 + dst0);
      gload16(Vbase + voff1, smem + 8192 + dst1);
    }
    __syncthreads();

    for (int t = 0; t <= tl; ++t) {
      if (t < tl) {  // issue next tile into other buffer (overlaps compute)
        char* bK = smem + (cur ^ 1) * 16384;
        const ushort_t* Ksrc = Kb + qkbase + (size_t)((t + 1) * 64) * D_;
        const ushort_t* Vsrc = Vbase + (t + 1) * 64;
        gload16(Ksrc + koff0, bK + dst0);
        gload16(Ksrc + koff1, bK + dst1);
        gload16(Vsrc + voff0, bK + 8192 + dst0);
        gload16(Vsrc + voff1, bK + 8192 + dst1);
      }
      char* bK = smem + cur * 16384;
      char* bV = bK + 8192;

      // St[kv][q] = K Q^T (swapped): A-frag = K rows, B-frag = Q rows
      f32x4 sc[4] = {};
      __builtin_amdgcn_s_setprio(1);
#pragma unroll
      for (int ks = 0; ks < 2; ++ks)
#pragma unroll
        for (int nt = 0; nt < 4; ++nt) {
          int rk = nt * 16 + l16;
          bf16x8 kf = *(const bf16x8*)(bK + rk * 128 + ((ks * 64 + lg * 16) ^ ((rk & 7) << 4)));
          sc[nt] = mfma16(kf, qf[ks], sc[nt]);
        }
      __builtin_amdgcn_s_setprio(0);
      if (t == tl) {  // causal mask on diagonal tile: kv row = t*64+nt*16+lg*4+r
#pragma unroll
        for (int nt = 0; nt < 4; ++nt)
#pragma unroll
          for (int r = 0; r < 4; ++r) {
            int kg = t * 64 + nt * 16 + lg * 4 + r;
            if (kg > qg0) sc[nt][r] = -1e30f;
          }
      }
      // tile max for this lane's q-row: per-thread tree + 2 shuffles
      float v = sc[0][0];
#pragma unroll
      for (int nt = 0; nt < 4; ++nt)
#pragma unroll
        for (int r = 0; r < 4; ++r) v = fmaxf(v, sc[nt][r]);
      v = fmaxf(v, __shfl_xor(v, 16));
      v = fmaxf(v, __shfl_xor(v, 32));
      // defer-rescale: skip when no q-row's max grew
      if (!__all(v <= m)) {
        float mn = fmaxf(m, v);
        float alpha = exp2f(m - mn);
        m = mn;
        lsum *= alpha;
#pragma unroll
        for (int r = 0; r < 4; ++r) {
          float ar = __shfl(alpha, lg * 4 + r);  // alpha for acc row q=lg*4+r
#pragma unroll
          for (int nt = 0; nt < 4; ++nt) acc_o[nt][r] *= ar;
        }
      }
      // P = exp2(S - m), row-sum, vectorized b64 P-writes (4 consecutive kv)
      float rs = 0.f;
#pragma unroll
      for (int nt = 0; nt < 4; ++nt) {
        usv4 pk;
#pragma unroll
        for (int r = 0; r < 4; ++r) {
          float p = exp2f(sc[nt][r] - m);
          rs += p;
          pk[r] = f2bf(p);
        }
        *(usv4*)(sP + pbase + ((nt * 32 + lg * 8) ^ pwsw)) = pk;
      }
      rs += __shfl_xor(rs, 16);
      rs += __shfl_xor(rs, 32);
      lsum += rs;
      // O += P V: A-frag = P rows (q=l16), B-frag = Vt rows (d)
      __builtin_amdgcn_s_setprio(1);
#pragma unroll
      for (int ks = 0; ks < 2; ++ks) {
        bf16x8 pa = *(const bf16x8*)(sP + pbase + ((ks * 64 + lg * 16) ^ pwsw));
#pragma unroll
        for (int nt = 0; nt < 4; ++nt) {
          int dr = nt * 16 + l16;
          bf16x8 vb = *(const bf16x8*)(bV + dr * 128 + ((ks * 64 + lg * 16) ^ ((dr & 7) << 4)));
          acc_o[nt] = mfma16(pa, vb, acc_o[nt]);
        }
      }
      __builtin_amdgcn_s_setprio(0);
      __syncthreads();  // all waves done with cur; next tile's loads landed
      cur ^= 1;
    }
    // epilogue: normalize (lsum lives at lane q; broadcast per acc row)
#pragma unroll
    for (int r = 0; r < 4; ++r) {
      float inv = 1.f / __shfl(lsum, lg * 4 + r);
      int qg = q0 + lg * 4 + r;
      ushort_t* crow = ctx + qkbase + (size_t)qg * D_;
#pragma unroll
      for (int nt = 0; nt < 4; ++nt) crow[nt * 16 + l16] = f2b(acc_o[nt][r] * inv);
    }
  }
}

// ---------------------------------------------------------------------------
extern "C" void kernel_launch(void* const* d_in, const int* in_sizes, int n_in,
                              void* d_out, int out_size, void* d_ws, size_t ws_size,
                              hipStream_t stream) {
  const float* query = (const float*)d_in[0];
  const float* key   = (const float*)d_in[1];
  const float* value = (const float*)d_in[2];
  const float* Wq    = (const float*)d_in[3];
  const float* Wk    = (const float*)d_in[4];
  const float* Wv    = (const float*)d_in[5];
  const float* Wo    = (const float*)d_in[6];

  char* ws = (char*)d_ws;
  const size_t SZ = (size_t)B_ * S_ * D_ * 2;  // 8 MB
  const size_t WSZ = (size_t)D_ * D_ * 2;      // 2 MB
  ushort_t* xq  = (ushort_t*)(ws + 0 * SZ);
  ushort_t* xk  = (ushort_t*)(ws + 1 * SZ);
  ushort_t* xv  = (ushort_t*)(ws + 2 * SZ);
  ushort_t* Qb  = (ushort_t*)(ws + 3 * SZ);
  ushort_t* Kb  = (ushort_t*)(ws + 4 * SZ);
  ushort_t* Vt  = (ushort_t*)(ws + 5 * SZ);  // [D][B*S] pre-transposed V
  ushort_t* ctx = xq;                        // xq dead after QKV projection
  ushort_t* wqb = (ushort_t*)(ws + 6 * SZ + 0 * WSZ);
  ushort_t* wkb = (ushort_t*)(ws + 6 * SZ + 1 * WSZ);
  ushort_t* wvb = (ushort_t*)(ws + 6 * SZ + 2 * WSZ);
  ushort_t* wob = (ushort_t*)(ws + 6 * SZ + 3 * WSZ);

  const int n8a = B_ * S_ * D_ / 8;  // 524288
  const int n8w = D_ * D_ / 8;       // 131072
  cvt3_kernel<<<dim3(n8a / 256, 3), 256, 0, stream>>>(query, key, value, xq, xk, xv);
  cvt4_kernel<<<dim3(n8w / 256, 4), 256, 0, stream>>>(Wq, Wk, Wv, Wo, wqb, wkb, wvb, wob);

  qkv_gemm<<<dim3(32, 8, 3), 256, 0, stream>>>(xq, xk, xv, wqb, wkb, wvb, Qb, Kb, Vt);

  attn_kernel<<<dim3(B_ * H_, 16), 256, 0, stream>>>(Qb, Kb, Vt, ctx);

  out_gemm<<<dim3(D_ / 64, (B_ * S_) / 128), 256, 0, stream>>>(ctx, wob, (float*)d_out);
}

// Round 13
// 213.695 us; speedup vs baseline: 1.6055x; 1.0180x over previous
//
#include <hip/hip_runtime.h>
#include <hip/hip_bf16.h>
#include <cstdint>

// ---------------------------------------------------------------------------
// MHA forward, fp32 in/out, bf16 MFMA internally.
// B=2 S=2048 D=1024 H=16 DH=64.
// R8..R12: attn VALU trim — defer-rescale THR=8 (rescale ~1x/q-tile instead
//     of every tile), compiler cvt_pk for P->bf16, max3/pairwise reduce trees,
//     running staging pointers. cvt3+cvt4 merged into one dispatch.
// Workspace (56 MB): [0,8M) xq/ctx [8,16) xk [16,24) xv
//   [24,32) Qb [32,40) Kb [40,48) Vt[D][B*S] [48,56) weights bf16 x4
// ---------------------------------------------------------------------------

typedef __attribute__((ext_vector_type(8))) __bf16 bf16x8;
typedef __attribute__((ext_vector_type(4))) __bf16 bf16x4;
typedef __attribute__((ext_vector_type(8))) unsigned short ushort8;
typedef __attribute__((ext_vector_type(4))) float f32x4;
typedef unsigned short ushort_t;

#define B_ 2
#define S_ 2048
#define D_ 1024
#define H_ 16
#define DH_ 64
#define BK 64

// 1/sqrt(DH) * log2(e): scores land pre-scaled for exp2-domain softmax
#define QSCALE 0.1803368801111244f

__device__ __forceinline__ ushort_t f2b(float f) {  // RNE
  uint32_t u = __builtin_bit_cast(uint32_t, f);
  u += 0x7fffu + ((u >> 16) & 1u);
  return (ushort_t)(u >> 16);
}

__device__ __forceinline__ f32x4 mfma16(bf16x8 a, bf16x8 b, f32x4 c) {
  return __builtin_amdgcn_mfma_f32_16x16x32_bf16(a, b, c, 0, 0, 0);
}

// async global->LDS, 16B/lane: dest = wave-uniform base + lane*16 (linear).
__device__ __forceinline__ void gload16(const ushort_t* g, char* lds) {
  __builtin_amdgcn_global_load_lds(
      (__attribute__((address_space(1))) void*)(uintptr_t)g,
      (__attribute__((address_space(3))) void*)(uintptr_t)lds, 16, 0, 0);
}

// ---------------------------------------------------------------------------
// All 7 fp32->bf16 converts in ONE dispatch. grid = 6144 + 2048 blocks.
__global__ __launch_bounds__(256) void cvt_all(
    const float* __restrict__ q, const float* __restrict__ k,
    const float* __restrict__ v, const float* __restrict__ wq,
    const float* __restrict__ wk, const float* __restrict__ wv,
    const float* __restrict__ wo, ushort_t* __restrict__ dq,
    ushort_t* __restrict__ dk, ushort_t* __restrict__ dv,
    ushort_t* __restrict__ dwq, ushort_t* __restrict__ dwk,
    ushort_t* __restrict__ dwv, ushort_t* __restrict__ dwo) {
  const int gid = blockIdx.x;
  const float* src;
  ushort_t* dst;
  int i;
  if (gid < 6144) {  // activations: 3 x 2048 blocks
    int t = gid >> 11;
    src = t == 0 ? q : (t == 1 ? k : v);
    dst = t == 0 ? dq : (t == 1 ? dk : dv);
    i = (gid & 2047) * 256 + threadIdx.x;
  } else {  // weights: 4 x 512 blocks
    int g = gid - 6144;
    int t = g >> 9;
    src = t == 0 ? wq : (t == 1 ? wk : (t == 2 ? wv : wo));
    dst = t == 0 ? dwq : (t == 1 ? dwk : (t == 2 ? dwv : dwo));
    i = (g & 511) * 256 + threadIdx.x;
  }
  f32x4 a = ((const f32x4*)src)[i * 2];
  f32x4 b = ((const f32x4*)src)[i * 2 + 1];
  ushort8 o;
#pragma unroll
  for (int j = 0; j < 4; ++j) o[j] = f2b(a[j]);
#pragma unroll
  for (int j = 0; j < 4; ++j) o[4 + j] = f2b(b[j]);
  ((ushort8*)dst)[i] = o;
}

// ---------------------------------------------------------------------------
// C[M,N] = scale * A[M,K] * W[N,K]^T.  4 waves as 2x2. LDS rows 128B,
// swizzle byte^=(row&7)<<4; gload16 dest linear, source slot inv-swizzled.
// Variant A (qkv): m97 2-barrier single-buffer.
template <int TBM, int TBN, int OUTF32>
__device__ __forceinline__ void gemm_body(const ushort_t* __restrict__ A,
                                          const ushort_t* __restrict__ W,
                                          void* __restrict__ Cout,
                                          int M, int N, int K, float scale,
                                          int i0, int j0) {
  constexpr int MI = TBM / 32, NJ = TBN / 32;
  __shared__ char smem[(TBM + TBN) * BK * 2];
  char* sA = smem;
  char* sB = smem + TBM * BK * 2;
  const int tid = threadIdx.x;
  const int w = tid >> 6, lane = tid & 63, l16 = lane & 15, lg = lane >> 4;
  const int wr = (w >> 1) * (TBM / 2), wc = (w & 1) * (TBN / 2);
  f32x4 acc[MI][NJ] = {};
  const int nk = K / BK;
  for (int kt = 0; kt < nk; ++kt) {
    const int k0 = kt * BK;
    __syncthreads();
#pragma unroll
    for (int is = 0; is < MI; ++is) {
      int chunk = is * 256 + tid;
      int row = chunk >> 3, s = chunk & 7, sl = s ^ (row & 7);
      gload16(A + (size_t)(i0 + row) * K + k0 + sl * 8, sA + (is * 4 + w) * 1024);
    }
#pragma unroll
    for (int is = 0; is < NJ; ++is) {
      int chunk = is * 256 + tid;
      int row = chunk >> 3, s = chunk & 7, sl = s ^ (row & 7);
      gload16(W + (size_t)(j0 + row) * K + k0 + sl * 8, sB + (is * 4 + w) * 1024);
    }
    __syncthreads();
#pragma unroll
    for (int ks = 0; ks < 2; ++ks) {
      bf16x8 af[MI], bfr[NJ];
#pragma unroll
      for (int mi = 0; mi < MI; ++mi) {
        int r = wr + mi * 16 + l16;
        af[mi] = *(const bf16x8*)(sA + r * 128 + ((ks * 64 + lg * 16) ^ ((r & 7) << 4)));
      }
#pragma unroll
      for (int nj = 0; nj < NJ; ++nj) {
        int r = wc + nj * 16 + l16;
        bfr[nj] = *(const bf16x8*)(sB + r * 128 + ((ks * 64 + lg * 16) ^ ((r & 7) << 4)));
      }
#pragma unroll
      for (int mi = 0; mi < MI; ++mi)
#pragma unroll
        for (int nj = 0; nj < NJ; ++nj)
          acc[mi][nj] = mfma16(af[mi], bfr[nj], acc[mi][nj]);
    }
  }
#pragma unroll
  for (int mi = 0; mi < MI; ++mi)
#pragma unroll
    for (int nj = 0; nj < NJ; ++nj)
#pragma unroll
      for (int r = 0; r < 4; ++r) {
        int row = i0 + wr + mi * 16 + lg * 4 + r;
        int col = j0 + wc + nj * 16 + l16;
        float v = acc[mi][nj][r] * scale;
        if (OUTF32)
          ((float*)Cout)[(size_t)row * N + col] = v;
        else
          ((ushort_t*)Cout)[(size_t)row * N + col] = f2b(v);
      }
}

// Variant B (out): double-buffered, stage(t+1) -> compute(t) -> 1 barrier.
// [A/B result, R3-vs-R8 totals: NULL vs gemm_body — matches m99/m100.]
template <int TBM, int TBN, int OUTF32>
__device__ __forceinline__ void gemm_db(const ushort_t* __restrict__ A,
                                        const ushort_t* __restrict__ W,
                                        void* __restrict__ Cout,
                                        int M, int N, int K, float scale,
                                        int i0, int j0) {
  constexpr int MI = TBM / 32, NJ = TBN / 32;
  constexpr int BUFB = (TBM + TBN) * BK * 2;
  __shared__ char smem[2 * BUFB];
  const int tid = threadIdx.x;
  const int w = tid >> 6, lane = tid & 63, l16 = lane & 15, lg = lane >> 4;
  const int wr = (w >> 1) * (TBM / 2), wc = (w & 1) * (TBN / 2);
  f32x4 acc[MI][NJ] = {};
  const int nk = K / BK;

  auto stage = [&](int kt, int buf) {
    char* sA = smem + buf * BUFB;
    char* sB = sA + TBM * BK * 2;
    const int k0 = kt * BK;
#pragma unroll
    for (int is = 0; is < MI; ++is) {
      int chunk = is * 256 + tid;
      int row = chunk >> 3, s = chunk & 7, sl = s ^ (row & 7);
      gload16(A + (size_t)(i0 + row) * K + k0 + sl * 8, sA + (is * 4 + w) * 1024);
    }
#pragma unroll
    for (int is = 0; is < NJ; ++is) {
      int chunk = is * 256 + tid;
      int row = chunk >> 3, s = chunk & 7, sl = s ^ (row & 7);
      gload16(W + (size_t)(j0 + row) * K + k0 + sl * 8, sB + (is * 4 + w) * 1024);
    }
  };

  stage(0, 0);
  __syncthreads();
  int cur = 0;
  for (int kt = 0; kt < nk; ++kt) {
    if (kt + 1 < nk) stage(kt + 1, cur ^ 1);
    char* sA = smem + cur * BUFB;
    char* sB = sA + TBM * BK * 2;
#pragma unroll
    for (int ks = 0; ks < 2; ++ks) {
      bf16x8 af[MI], bfr[NJ];
#pragma unroll
      for (int mi = 0; mi < MI; ++mi) {
        int r = wr + mi * 16 + l16;
        af[mi] = *(const bf16x8*)(sA + r * 128 + ((ks * 64 + lg * 16) ^ ((r & 7) << 4)));
      }
#pragma unroll
      for (int nj = 0; nj < NJ; ++nj) {
        int r = wc + nj * 16 + l16;
        bfr[nj] = *(const bf16x8*)(sB + r * 128 + ((ks * 64 + lg * 16) ^ ((r & 7) << 4)));
      }
#pragma unroll
      for (int mi = 0; mi < MI; ++mi)
#pragma unroll
        for (int nj = 0; nj < NJ; ++nj)
          acc[mi][nj] = mfma16(af[mi], bfr[nj], acc[mi][nj]);
    }
    __syncthreads();  // drains vmcnt: next buf ready; all waves done with cur
    cur ^= 1;
  }
#pragma unroll
  for (int mi = 0; mi < MI; ++mi)
#pragma unroll
    for (int nj = 0; nj < NJ; ++nj)
#pragma unroll
      for (int r = 0; r < 4; ++r) {
        int row = i0 + wr + mi * 16 + lg * 4 + r;
        int col = j0 + wc + nj * 16 + l16;
        float v = acc[mi][nj][r] * scale;
        if (OUTF32)
          ((float*)Cout)[(size_t)row * N + col] = v;
        else
          ((ushort_t*)Cout)[(size_t)row * N + col] = f2b(v);
      }
}

// One dispatch for Q, K, and transposed-V projections. grid (32, 8, 3).
__global__ __launch_bounds__(256) void qkv_gemm(
    const ushort_t* __restrict__ xq, const ushort_t* __restrict__ xk,
    const ushort_t* __restrict__ xv, const ushort_t* __restrict__ wq,
    const ushort_t* __restrict__ wk, const ushort_t* __restrict__ wv,
    ushort_t* __restrict__ Qb, ushort_t* __restrict__ Kb,
    ushort_t* __restrict__ Vt) {
  const int z = blockIdx.z;
  if (z < 2) {
    gemm_body<128, 128, 0>(z ? xk : xq, z ? wk : wq, z ? Kb : Qb,
                           B_ * S_, D_, D_, z ? 1.f : QSCALE,
                           blockIdx.x * 128, blockIdx.y * 128);
  } else {
    // Vt[d][s] = sum_k Wv[d][k] * xv[s][k] : operand swap, M=D, N=B*S
    gemm_body<128, 128, 0>(wv, xv, Vt, D_, B_ * S_, D_, 1.f,
                           blockIdx.y * 128, blockIdx.x * 128);
  }
}

__global__ __launch_bounds__(256) void out_gemm(const ushort_t* __restrict__ ctx,
                                                const ushort_t* __restrict__ wo,
                                                float* __restrict__ out) {
  gemm_db<128, 64, 1>(ctx, wo, out, B_ * S_, D_, D_, 1.f,
                      blockIdx.y * 128, blockIdx.x * 64);
}

// ---------------------------------------------------------------------------
// Flash attention, causal, exp2-domain, SWAPPED QK^T.
// grid = (B*H, 16 pairs) -> linear%8 = bh%8 -> 4 heads per XCD (K/V L2-local).
// 256 threads = 4 waves; block does q-tiles {p, 31-p} (64 rows each), 33 iters.
// Swapped St = mfma(K,Q): col=q=l16 (lane-local q-row), row=kv=lg*4+r+16nt.
// LDS: dbuf (sK[64][128B] + sVt[64][128B]) x2 = 32KB, sP 4x2KB.
__global__ __launch_bounds__(256) void attn_kernel(
    const ushort_t* __restrict__ Qb, const ushort_t* __restrict__ Kb,
    const ushort_t* __restrict__ VtG, ushort_t* __restrict__ ctx) {
  const int bh = blockIdx.x;
  const int pair = blockIdx.y;
  const int b = bh >> 4, h = bh & 15;
  const int tid = threadIdx.x;
  const int w = tid >> 6, lane = tid & 63, l16 = lane & 15, lg = lane >> 4;

  __shared__ char smem[2 * 16384 + 4 * 2048];
  char* sP = smem + 32768 + w * 2048;

  const size_t BS = (size_t)B_ * S_;
  const size_t qkbase = ((size_t)b * S_) * D_ + h * DH_;
  const ushort_t* Vbase = VtG + (size_t)(h * 64) * BS + (size_t)b * S_;

  // staging offsets (per-thread constants)
  const int srow = tid >> 3, sslot = (tid & 7) ^ (srow & 7);
  const size_t koff0 = (size_t)srow * D_ + sslot * 8;
  const size_t koff1 = koff0 + (size_t)32 * D_;
  const size_t voff0 = (size_t)srow * BS + sslot * 8;
  const size_t voff1 = voff0 + (size_t)32 * BS;
  const int dst0 = w * 1024, dst1 = 4096 + w * 1024;

  // P-write swizzled byte offsets (per nt), and A-frag read offsets
  const int pwsw = (l16 & 7) << 4;
  const int pbase = l16 * 128;

  for (int sub = 0; sub < 2; ++sub) {
    const int qt = sub ? (31 - pair) : pair;
    const int q0 = qt * 64 + w * 16;
    const int qg0 = q0 + l16;  // this lane's q row (swapped layout)
    const int tl = qt;

    bf16x8 qf[2];
    {
      const ushort_t* qrow = Qb + qkbase + (size_t)qg0 * D_;
      qf[0] = *(const bf16x8*)(qrow + lg * 8);
      qf[1] = *(const bf16x8*)(qrow + 32 + lg * 8);
    }

    f32x4 acc_o[4] = {};
    float m = -1e30f, lsum = 0.f;

    int cur = 0;
    {  // stage tile 0 -> buf 0
      const ushort_t* Ksrc = Kb + qkbase;
      gload16(Ksrc + koff0, smem + dst0);
      gload16(Ksrc + koff1, smem + dst1);
      gload16(Vbase + voff0, smem + 8192 + dst0);
      gload16(Vbase + voff1, smem + 8192 + dst1);
    }
    __syncthreads();

    const ushort_t* Kst = Kb + qkbase + (size_t)64 * D_;  // next-tile ptrs
    const ushort_t* Vst = Vbase + 64;
    for (int t = 0; t <= tl; ++t) {
      if (t < tl) {  // issue next tile into other buffer (overlaps compute)
        char* bK = smem + (cur ^ 1) * 16384;
        gload16(Kst + koff0, bK + dst0);
        gload16(Kst + koff1, bK + dst1);
        gload16(Vst + voff0, bK + 8192 + dst0);
        gload16(Vst + voff1, bK + 8192 + dst1);
        Kst += (size_t)64 * D_;
        Vst += 64;
      }
      char* bK = smem + cur * 16384;
      char* bV = bK + 8192;

      // St[kv][q] = K Q^T (swapped): A-frag = K rows, B-frag = Q rows
      f32x4 sc[4] = {};
      __builtin_amdgcn_s_setprio(1);
#pragma unroll
      for (int ks = 0; ks < 2; ++ks)
#pragma unroll
        for (int nt = 0; nt < 4; ++nt) {
          int rk = nt * 16 + l16;
          bf16x8 kf = *(const bf16x8*)(bK + rk * 128 + ((ks * 64 + lg * 16) ^ ((rk & 7) << 4)));
          sc[nt] = mfma16(kf, qf[ks], sc[nt]);
        }
      __builtin_amdgcn_s_setprio(0);
      if (t == tl) {  // causal mask on diagonal tile: kv row = t*64+nt*16+lg*4+r
#pragma unroll
        for (int nt = 0; nt < 4; ++nt)
#pragma unroll
          for (int r = 0; r < 4; ++r) {
            int kg = t * 64 + nt * 16 + lg * 4 + r;
            if (kg > qg0) sc[nt][r] = -1e30f;
          }
      }
      // tile max for this lane's q-row: max3-fusable triples, then 2 shuffles
      float a0 = fmaxf(fmaxf(sc[0][0], sc[0][1]), sc[0][2]);
      float a1 = fmaxf(fmaxf(sc[0][3], sc[1][0]), sc[1][1]);
      float a2 = fmaxf(fmaxf(sc[1][2], sc[1][3]), sc[2][0]);
      float a3 = fmaxf(fmaxf(sc[2][1], sc[2][2]), sc[2][3]);
      float a4 = fmaxf(fmaxf(sc[3][0], sc[3][1]), sc[3][2]);
      float v = fmaxf(fmaxf(fmaxf(a0, a1), fmaxf(a2, a3)), fmaxf(a4, sc[3][3]));
      v = fmaxf(v, __shfl_xor(v, 16));
      v = fmaxf(v, __shfl_xor(v, 32));
      // defer-rescale, THR=8 log2-units: with score-spread ~0.6 units/σ a
      // growth of >8 is ~never — rescale fires ~once per q-tile (t=0 init).
      // P may then reach 2^8; fp32 lsum/acc and bf16 relative precision OK.
      if (!__all(v <= m + 8.f)) {
        float mn = fmaxf(m, v);
        float alpha = exp2f(m - mn);
        m = mn;
        lsum *= alpha;
#pragma unroll
        for (int r = 0; r < 4; ++r) {
          float ar = __shfl(alpha, lg * 4 + r);  // alpha for acc row q=lg*4+r
#pragma unroll
          for (int nt = 0; nt < 4; ++nt) acc_o[nt][r] *= ar;
        }
      }
      // P = exp2(S - m); bf16 via compiler cvt_pk; pairwise-tree row-sum
      float pe[4][4];
#pragma unroll
      for (int nt = 0; nt < 4; ++nt)
#pragma unroll
        for (int r = 0; r < 4; ++r) pe[nt][r] = exp2f(sc[nt][r] - m);
#pragma unroll
      for (int nt = 0; nt < 4; ++nt) {
        bf16x4 pk;
#pragma unroll
        for (int r = 0; r < 4; ++r) pk[r] = (__bf16)pe[nt][r];
        *(bf16x4*)(sP + pbase + ((nt * 32 + lg * 8) ^ pwsw)) = pk;
      }
      float rs = ((pe[0][0] + pe[0][1]) + (pe[0][2] + pe[0][3]))
               + ((pe[1][0] + pe[1][1]) + (pe[1][2] + pe[1][3]));
      rs += ((pe[2][0] + pe[2][1]) + (pe[2][2] + pe[2][3]))
          + ((pe[3][0] + pe[3][1]) + (pe[3][2] + pe[3][3]));
      rs += __shfl_xor(rs, 16);
      rs += __shfl_xor(rs, 32);
      lsum += rs;
      // O += P V: A-frag = P rows (q=l16), B-frag = Vt rows (d)
      __builtin_amdgcn_s_setprio(1);
#pragma unroll
      for (int ks = 0; ks < 2; ++ks) {
        bf16x8 pa = *(const bf16x8*)(sP + pbase + ((ks * 64 + lg * 16) ^ pwsw));
#pragma unroll
        for (int nt = 0; nt < 4; ++nt) {
          int dr = nt * 16 + l16;
          bf16x8 vb = *(const bf16x8*)(bV + dr * 128 + ((ks * 64 + lg * 16) ^ ((dr & 7) << 4)));
          acc_o[nt] = mfma16(pa, vb, acc_o[nt]);
        }
      }
      __builtin_amdgcn_s_setprio(0);
      __syncthreads();  // all waves done with cur; next tile's loads landed
      cur ^= 1;
    }
    // epilogue: normalize (lsum lives at lane q; broadcast per acc row)
#pragma unroll
    for (int r = 0; r < 4; ++r) {
      float inv = 1.f / __shfl(lsum, lg * 4 + r);
      int qg = q0 + lg * 4 + r;
      ushort_t* crow = ctx + qkbase + (size_t)qg * D_;
#pragma unroll
      for (int nt = 0; nt < 4; ++nt) crow[nt * 16 + l16] = f2b(acc_o[nt][r] * inv);
    }
  }
}

// ---------------------------------------------------------------------------
extern "C" void kernel_launch(void* const* d_in, const int* in_sizes, int n_in,
                              void* d_out, int out_size, void* d_ws, size_t ws_size,
                              hipStream_t stream) {
  const float* query = (const float*)d_in[0];
  const float* key   = (const float*)d_in[1];
  const float* value = (const float*)d_in[2];
  const float* Wq    = (const float*)d_in[3];
  const float* Wk    = (const float*)d_in[4];
  const float* Wv    = (const float*)d_in[5];
  const float* Wo    = (const float*)d_in[6];

  char* ws = (char*)d_ws;
  const size_t SZ = (size_t)B_ * S_ * D_ * 2;  // 8 MB
  const size_t WSZ = (size_t)D_ * D_ * 2;      // 2 MB
  ushort_t* xq  = (ushort_t*)(ws + 0 * SZ);
  ushort_t* xk  = (ushort_t*)(ws + 1 * SZ);
  ushort_t* xv  = (ushort_t*)(ws + 2 * SZ);
  ushort_t* Qb  = (ushort_t*)(ws + 3 * SZ);
  ushort_t* Kb  = (ushort_t*)(ws + 4 * SZ);
  ushort_t* Vt  = (ushort_t*)(ws + 5 * SZ);  // [D][B*S] pre-transposed V
  ushort_t* ctx = xq;                        // xq dead after QKV projection
  ushort_t* wqb = (ushort_t*)(ws + 6 * SZ + 0 * WSZ);
  ushort_t* wkb = (ushort_t*)(ws + 6 * SZ + 1 * WSZ);
  ushort_t* wvb = (ushort_t*)(ws + 6 * SZ + 2 * WSZ);
  ushort_t* wob = (ushort_t*)(ws + 6 * SZ + 3 * WSZ);

  cvt_all<<<8192, 256, 0, stream>>>(query, key, value, Wq, Wk, Wv, Wo,
                                    xq, xk, xv, wqb, wkb, wvb, wob);

  qkv_gemm<<<dim3(32, 8, 3), 256, 0, stream>>>(xq, xk, xv, wqb, wkb, wvb, Qb, Kb, Vt);

  attn_kernel<<<dim3(B_ * H_, 16), 256, 0, stream>>>(Qb, Kb, Vt, ctx);

  out_gemm<<<dim3(D_ / 64, (B_ * S_) / 128), 256, 0, stream>>>(ctx, wob, (float*)d_out);
}